// Round 1
// 286.229 us; speedup vs baseline: 1.0066x; 1.0066x over previous
//
#include <hip/hip_runtime.h>

#define RADIUS 20
#define KSIZE  41
#define ALPHA_F 50.0f
#define TY     16
#define WID    512
#define HEI    512
#define PW     (WID + 2 * RADIUS)   // 552 floats per padded LDS row
#define NRH    48                   // input rows per 8-output half-band (8 + 2*RADIUS)
#define PF     8                    // phase-1 prefetch depth (rows), power of 2

// Normalized Gaussian taps, sigma=5, radius=20: w[t]=exp(-0.5*((t-20)/5)^2)/S,
// S = 12.53263858. Baked literals; fully-unrolled loops fold these to constants.
__device__ constexpr float G[KSIZE] = {
    2.6770e-05f, 5.8390e-05f, 1.22380e-04f, 2.46460e-04f, 4.76840e-04f,
    8.86410e-04f, 1.583160e-03f, 2.716710e-03f, 4.479090e-03f, 7.095210e-03f,
    1.0798630e-02f, 1.5790680e-02f, 2.2185070e-02f, 2.9946720e-02f, 3.8838800e-02f,
    4.8396120e-02f, 5.7940680e-02f, 6.6647650e-02f, 7.3657040e-02f, 7.8211730e-02f,
    7.9791720e-02f,
    7.8211730e-02f, 7.3657040e-02f, 6.6647650e-02f, 5.7940680e-02f, 4.8396120e-02f,
    3.8838800e-02f, 2.9946720e-02f, 2.2185070e-02f, 1.5790680e-02f, 1.0798630e-02f,
    7.095210e-03f, 4.479090e-03f, 2.716710e-03f, 1.583160e-03f, 8.86410e-04f,
    4.76840e-04f, 2.46460e-04f, 1.22380e-04f, 5.8390e-05f, 2.6770e-05f
};

__device__ __forceinline__ int refl(int i, int n) {
    // scipy 'reflect' (edge included); exact for i in [-n, 2n-1]
    i = (i < 0) ? (-1 - i) : i;
    i = (i >= n) ? (2 * n - 1 - i) : i;
    return i;
}

// reflect for warp coords; exact for i in [-512, 1023] (we clamp into that range)
__device__ __forceinline__ int refl512(int i) {
    i = (i < 0) ? (-1 - i) : i;
    return (i >= 512) ? (1023 - i) : i;
}

// Vertical 41-tap blur of 8 consecutive output rows x 4 columns.
// src points at (field + batch_base + 4*c4); absolute row ybase..ybase+47.
// INTERIOR: rows are in [0, HEI) -> static addressing, no refl, no cndmask.
template<bool INTERIOR>
__device__ __forceinline__ void vblur8(const float* __restrict__ src, int ybase,
                                       float acc[8][4]) {
    float bx[PF][4];
    #pragma unroll
    for (int k = 0; k < PF; ++k) {
        const int gy = INTERIOR ? (ybase + k) : refl(ybase + k, HEI);
        const float4 v = *reinterpret_cast<const float4*>(src + (size_t)gy * WID);
        bx[k][0] = v.x; bx[k][1] = v.y; bx[k][2] = v.z; bx[k][3] = v.w;
    }
    #pragma unroll
    for (int r = 0; r < NRH; ++r) {
        float v[4];
        #pragma unroll
        for (int j = 0; j < 4; ++j) v[j] = bx[r & (PF - 1)][j];   // static after unroll
        if (r + PF < NRH) {                                       // prefetch row r+PF
            const int gy = INTERIOR ? (ybase + r + PF) : refl(ybase + r + PF, HEI);
            const float4 nv = *reinterpret_cast<const float4*>(src + (size_t)gy * WID);
            bx[r & (PF - 1)][0] = nv.x; bx[r & (PF - 1)][1] = nv.y;
            bx[r & (PF - 1)][2] = nv.z; bx[r & (PF - 1)][3] = nv.w;
        }
        #pragma unroll
        for (int o = 0; o < 8; ++o) {
            const int t = r - o;                                  // static after unroll
            if (t >= 0 && t < KSIZE) {
                const float g = G[t];
                #pragma unroll
                for (int j = 0; j < 4; ++j) acc[o][j] = fmaf(g, v[j], acc[o][j]);
            }
        }
    }
}

__global__ __launch_bounds__(512) void elastic_kernel(
    const float* __restrict__ xin, const float* __restrict__ rdx,
    const float* __restrict__ rdy, float* __restrict__ outp, int B) {

    __shared__ float sdx[TY][PW];   // 16 * 552 * 4 B = 35.3 KB
    __shared__ float sdy[TY][PW];   // total 70.6 KB -> 2 blocks/CU

    const int tid = threadIdx.x;

    // Block decode. For B==64: XCD-aware swizzle — give each XCD 8 whole batches
    // swept band-by-band so each batch's fields + image stay hot in that XCD's L2.
    int b, band;
    {
        const int L = blockIdx.x;
        if (B == 64) {
            const int xcd = L & 7;
            const int s   = L >> 3;          // 0..255
            b    = xcd * 8 + (s >> 5);       // 8 batches per XCD
            band = s & 31;
        } else {
            b    = L / (HEI / TY);
            band = L % (HEI / TY);
        }
    }
    const int y0 = band * TY;
    const size_t base = (size_t)b * (HEI * WID);

    // ---------------- phase 1: vertical 41-tap blur of (2*r-1) ----------------
    // 512 threads = 128 col-groups (float4) x 2 fields x 2 row-halves.
    // Each thread: 4 columns, 8 output rows, one field -> 48 float4 loads,
    // 1312 FMAs. Loads/refl/addressing amortized 4x vs the scalar-column layout.
    {
        const int c4 = tid & 127;            // float4 column group: cols 4*c4..4*c4+3
        const int f  = (tid >> 7) & 1;       // field select (wave-uniform)
        const int h  = tid >> 8;             // row half (wave-uniform)
        const int ybase = y0 + 8 * h - RADIUS;

        const float* src = (f ? rdy : rdx) + base + 4 * c4;

        float acc[8][4];
        #pragma unroll
        for (int o = 0; o < 8; ++o)
            #pragma unroll
            for (int j = 0; j < 4; ++j) acc[o][j] = 0.f;

        // 28 of 32 bands are fully interior for both halves
        if (ybase >= 0 && ybase + NRH <= HEI) vblur8<true >(src, ybase, acc);
        else                                  vblur8<false>(src, ybase, acc);

        float (*sd)[PW] = f ? sdy : sdx;     // wave-uniform select

        #pragma unroll
        for (int o = 0; o < 8; ++o) {
            const int row = 8 * h + o;       // 0..15
            float sv[4];
            #pragma unroll
            for (int j = 0; j < 4; ++j) sv[j] = 2.f * acc[o][j] - 1.f; // affine commutes with blur
            float4 pack;
            pack.x = sv[0]; pack.y = sv[1]; pack.z = sv[2]; pack.w = sv[3];
            *reinterpret_cast<float4*>(&sd[row][RADIUS + 4 * c4]) = pack;
            if (c4 < 5) {                    // cols 0..19 reflect to left halo
                #pragma unroll
                for (int j = 0; j < 4; ++j) sd[row][RADIUS - 1 - (4 * c4 + j)] = sv[j];
            }
            if (c4 >= 123) {                 // cols 492..511 reflect to right halo
                #pragma unroll
                for (int j = 0; j < 4; ++j) sd[row][RADIUS + 2 * WID - 1 - (4 * c4 + j)] = sv[j];
            }
        }
    }
    __syncthreads();

    // ---------- phase 2: horizontal 41-tap blur (*ALPHA) + bilinear warp ----------
    const int c4 = tid & 127;          // float4 index -> cols 4*c4..4*c4+3
    const int rg = tid >> 7;           // 0..3 (wave-uniform)
    const float* img = xin + base;

    #pragma unroll
    for (int i = 0; i < 4; ++i) {
        const int o  = rg + 4 * i;     // rows 0..15
        const int gy = y0 + o;

        float dxv[4] = {0.f, 0.f, 0.f, 0.f};
        float dyv[4] = {0.f, 0.f, 0.f, 0.f};

        {   // 11 aligned float4 LDS reads -> 44-float window, 41-tap FMA x 4 cols
            float w[44];
            const float4* rp = (const float4*)(&sdx[o][0]);
            #pragma unroll
            for (int q = 0; q < 11; ++q) {
                const float4 v = rp[c4 + q];
                w[4 * q + 0] = v.x; w[4 * q + 1] = v.y;
                w[4 * q + 2] = v.z; w[4 * q + 3] = v.w;
            }
            #pragma unroll
            for (int t = 0; t < KSIZE; ++t) {
                const float g = G[t];
                #pragma unroll
                for (int j = 0; j < 4; ++j) dxv[j] = fmaf(g, w[t + j], dxv[j]);
            }
        }
        {
            float w[44];
            const float4* rp = (const float4*)(&sdy[o][0]);
            #pragma unroll
            for (int q = 0; q < 11; ++q) {
                const float4 v = rp[c4 + q];
                w[4 * q + 0] = v.x; w[4 * q + 1] = v.y;
                w[4 * q + 2] = v.z; w[4 * q + 3] = v.w;
            }
            #pragma unroll
            for (int t = 0; t < KSIZE; ++t) {
                const float g = G[t];
                #pragma unroll
                for (int j = 0; j < 4; ++j) dyv[j] = fmaf(g, w[t + j], dyv[j]);
            }
        }

        float st[4];
        #pragma unroll
        for (int j = 0; j < 4; ++j) {
            const int col = 4 * c4 + j;
            float xx = (float)col + dxv[j] * ALPHA_F;
            float yy = (float)gy  + dyv[j] * ALPHA_F;
            // legit range is (-50, 562); clamp keeps refl512 exact and kills NaN/inf
            xx = fminf(fmaxf(xx, -511.f), 1022.f);
            yy = fminf(fmaxf(yy, -511.f), 1022.f);
            const float x0f = floorf(xx), y0f = floorf(yy);
            const float wx = xx - x0f, wy = yy - y0f;
            const int x0 = (int)x0f, yb = (int)y0f;
            const int x0r = refl512(x0);
            const int x1r = refl512(x0 + 1);
            const int y0r = refl512(yb);
            const int y1r = refl512(yb + 1);

            const float* r0 = img + ((size_t)y0r << 9);
            const float* r1 = img + ((size_t)y1r << 9);
            const float v00 = r0[x0r];
            const float v01 = r0[x1r];
            const float v10 = r1[x0r];
            const float v11 = r1[x1r];

            const float top = fmaf(wx, v01 - v00, v00);   // 3-lerp: 6 ops vs 11
            const float bot = fmaf(wx, v11 - v10, v10);
            st[j] = fmaf(wy, bot - top, top);
        }

        float4 pack;
        pack.x = st[0]; pack.y = st[1]; pack.z = st[2]; pack.w = st[3];
        *reinterpret_cast<float4*>(outp + base + (size_t)gy * WID + 4 * c4) = pack;
    }
}

extern "C" void kernel_launch(void* const* d_in, const int* in_sizes, int n_in,
                              void* d_out, int out_size, void* d_ws, size_t ws_size,
                              hipStream_t stream) {
    const float* x   = (const float*)d_in[0];
    const float* rdx = (const float*)d_in[1];
    const float* rdy = (const float*)d_in[2];
    float* out = (float*)d_out;

    const int B = in_sizes[1] / (HEI * WID);   // 64

    const int nblocks = B * (HEI / TY);        // 2048
    elastic_kernel<<<nblocks, 512, 0, stream>>>(x, rdx, rdy, out, B);
    (void)d_ws; (void)ws_size; (void)n_in; (void)out_size;  // no workspace needed
}